// Round 8
// baseline (322.204 us; speedup 1.0000x reference)
//
#include <hip/hip_runtime.h>

// ---------------------------------------------------------------------------
// Round 20: revert conv4/5 to conv_so (R19's 1-wave/SIMD had zero TLP).
// K-loop rebuilt as copy-free A/B software pipeline: icb unrolled x2 (NICB is
// even everywhere) -> 18 static steps, bfrA/bfrB parity fixed at compile time,
// next step's 4 ds_read_b128 issued before current step's 16 MFMAs.
// (R17 died of scratch spill from its bfr=bfrN copy loop -- WRITE_SIZE 10x --
// not of the pipelining idea; this version has no copies.)
// CLS fused in conv5 with bf16 classifier weights (cwb). launch_bounds(256,2)
// for register headroom; VGPR ~150 still allows 3 waves/SIMD at runtime.
// ---------------------------------------------------------------------------

typedef __attribute__((ext_vector_type(8))) short short8;
typedef __attribute__((ext_vector_type(4))) float floatx4;
typedef unsigned int uint;
typedef unsigned short ushort;

__device__ __forceinline__ ushort f2bf(float f) {
    uint u = __float_as_uint(f);
    return (ushort)((u + 0x7fffu + ((u >> 16) & 1u)) >> 16);
}
__device__ __forceinline__ float bf2f(ushort h) {
    return __uint_as_float(((uint)h) << 16);
}

// async global->LDS, 16 bytes per lane, dest = wave-uniform base + lane*16
typedef const __attribute__((address_space(1))) unsigned int* gas_ptr;
typedef __attribute__((address_space(3))) unsigned int* las_ptr;
__device__ __forceinline__ void gload_lds16(const void* g, void* l) {
    __builtin_amdgcn_global_load_lds((gas_ptr)g, (las_ptr)l, 16, 0, 0);
}

// ---------------- fused weight transform (single launch) -------------------
__device__ __forceinline__ void wlin_one(
    const float* __restrict__ src, short* __restrict__ dst, int OC, int IC, int o)
{
    int j    = o & 7;
    int lane = (o >> 3) & 63;
    int r    = o >> 9;
    int G16  = OC >> 4;
    int g    = r % G16;  r /= G16;
    int kk   = r % 9;
    int icb  = r / 9;
    int oc = g * 16 + (lane & 15);
    int ic = icb * 32 + (lane >> 4) * 8 + j;
    dst[o] = (short)f2bf(src[((long)oc * IC + ic) * 9 + kk]);
}

#define N_W0 2048
#define N_W1 36864
#define N_W2 73728
#define N_W3 147456
#define N_W4 294912
#define N_W5 589824
#define N_CWB (100 * 4096)
#define N_WT_TOTAL (N_W0 + N_W1 + N_W2 + N_W3 + N_W4 + N_W5)
#define N_ALL (N_WT_TOTAL + N_CWB)

__global__ __launch_bounds__(256) void wtransform_all(
    const float* __restrict__ w0, const float* __restrict__ w1,
    const float* __restrict__ w2, const float* __restrict__ w3,
    const float* __restrict__ w4, const float* __restrict__ w5,
    const float* __restrict__ cw,
    short* __restrict__ wt0, short* __restrict__ wts1, short* __restrict__ wts2,
    short* __restrict__ wts3, short* __restrict__ wts4, short* __restrict__ wts5,
    short* __restrict__ zp, short* __restrict__ cwb)
{
    if (blockIdx.x == 0 && threadIdx.x < 32) zp[threadIdx.x] = 0;  // zero page
    int idx = blockIdx.x * 256 + threadIdx.x;
    if (idx < N_W0) {
        int oc = idx >> 5, k = idx & 31;
        wt0[idx] = (k < 27) ? (short)f2bf(w0[oc * 27 + k]) : (short)0;
        return;
    }
    idx -= N_W0;
    if (idx < N_W1) { wlin_one(w1, wts1, 64, 64, idx); return; }
    idx -= N_W1;
    if (idx < N_W2) { wlin_one(w2, wts2, 128, 64, idx); return; }
    idx -= N_W2;
    if (idx < N_W3) { wlin_one(w3, wts3, 128, 128, idx); return; }
    idx -= N_W3;
    if (idx < N_W4) { wlin_one(w4, wts4, 256, 128, idx); return; }
    idx -= N_W4;
    if (idx < N_W5) { wlin_one(w5, wts5, 256, 256, idx); return; }
    idx -= N_W5;
    if (idx < N_CWB) cwb[idx] = (short)f2bf(cw[idx]);
}

// ---------------- conv0 MFMA: 3->64 @32x32, NCHW fp32 in, NC8HW8 bf16 out
__global__ __launch_bounds__(256, 2) void conv0_mfma(
    const float* __restrict__ x, const short* __restrict__ wT0,
    const float* __restrict__ b0, ushort* __restrict__ out)
{
    __shared__ float  s_x[3 * 18 * 34];
    __shared__ ushort s_b[4 * 512 * 8];

    const int tid  = threadIdx.x;
    const int wv   = tid >> 6;
    const int lane = tid & 63;
    const int quad = lane >> 4;
    const int l16  = lane & 15;
    const int b    = blockIdx.x >> 1;
    const int r0   = (blockIdx.x & 1) * 16;

    for (int idx = tid; idx < 3 * 18 * 34; idx += 256) {
        int c   = idx / 612;
        int rem = idx - c * 612;
        int ry  = rem / 34, rx = rem - ry * 34;
        int gy  = r0 + ry - 1, gx = rx - 1;
        float v = 0.f;
        if (gy >= 0 && gy < 32 && gx >= 0 && gx < 32)
            v = x[(((long)b * 3 + c) * 32 + gy) * 32 + gx];
        s_x[idx] = v;
    }
    __syncthreads();

#pragma unroll
    for (int rep = 0; rep < 2; ++rep) {
        int pxl = rep * 256 + tid;
        int py = pxl >> 5, px = pxl & 31;
        ushort v[32];
#pragma unroll
        for (int c = 0; c < 3; ++c)
#pragma unroll
            for (int ky = 0; ky < 3; ++ky)
#pragma unroll
                for (int kx = 0; kx < 3; ++kx)
                    v[c * 9 + ky * 3 + kx] = f2bf(s_x[c * 612 + (py + ky) * 34 + (px + kx)]);
#pragma unroll
        for (int k = 27; k < 32; ++k) v[k] = 0;
#pragma unroll
        for (int q = 0; q < 4; ++q)
            *(uint4*)(&s_b[(q * 512 + pxl) * 8]) = *(const uint4*)(v + q * 8);
    }
    __syncthreads();

    floatx4 acc[4][8];
#pragma unroll
    for (int i = 0; i < 4; ++i)
#pragma unroll
        for (int t = 0; t < 8; ++t) acc[i][t] = (floatx4)0.f;

    short8 afr[4];
#pragma unroll
    for (int i = 0; i < 4; ++i)
        afr[i] = *(const short8*)(wT0 + (i * 16 + l16) * 32 + quad * 8);
#pragma unroll
    for (int t = 0; t < 8; ++t) {
        int pxl = wv * 128 + t * 16 + l16;
        short8 bfr = *(const short8*)(&s_b[(quad * 512 + pxl) * 8]);
#pragma unroll
        for (int i = 0; i < 4; ++i)
            acc[i][t] = __builtin_amdgcn_mfma_f32_16x16x32_bf16(afr[i], bfr, acc[i][t], 0, 0, 0);
    }

#pragma unroll
    for (int i = 0; i < 4; ++i) {
        int oc0 = i * 16 + quad * 4;
        float4 bv = *(const float4*)(b0 + oc0);
#pragma unroll
        for (int t = 0; t < 8; ++t) {
            int pxl = wv * 128 + t * 16 + l16;
            int py = pxl >> 5, px = pxl & 31;
            long dst = ((((long)b * 8 + (oc0 >> 3)) * 32 + r0 + py) * 32 + px) * 8 + (oc0 & 7);
            float v0 = acc[i][t][0] + bv.x;
            float v1 = acc[i][t][1] + bv.y;
            float v2 = acc[i][t][2] + bv.z;
            float v3 = acc[i][t][3] + bv.w;
            ushort o[4];
            o[0] = f2bf(v0 > 0.f ? v0 : 0.f);
            o[1] = f2bf(v1 > 0.f ? v1 : 0.f);
            o[2] = f2bf(v2 > 0.f ? v2 : 0.f);
            o[3] = f2bf(v3 > 0.f ? v3 : 0.f);
            *(uint2*)(out + dst) = *(uint2*)o;
        }
    }
}

// ---------------- stage-once conv3x3+ReLU (+pool, +optional classifier) ----
// Block = 4 waves, one strip of ROWS rows. Wave = 64 oc x 64 px (4x4 frags).
// K-loop: copy-free A/B act pipeline (icb unrolled x2, static parity) +
// depth-3 rotating weight prefetch.
template<int IC, int OC, int H, int W, int ROWS, int OCGROUPS, bool POOL, bool CLS>
__global__ __launch_bounds__(256, 2) void conv_so(
    const ushort* __restrict__ act_in,  // [B][IC/8][H][W][8]
    const short*  __restrict__ wTs,     // linear frag-order bf16
    const float*  __restrict__ bias,
    ushort* __restrict__ act_out,       // [B][OC/8][H'][W'][8] (pooled if POOL)
    const ushort* __restrict__ zp,      // 64B zero page
    const int*   __restrict__ tids,     // CLS only
    const short* __restrict__ cwb,      // CLS only (bf16)
    const float* __restrict__ cbv,      // CLS only
    float*       __restrict__ outp)     // CLS only
{
    constexpr int WPAD  = W + 2;
    constexpr int RPAD  = ROWS + 2;
    constexpr int UNITS = RPAD * WPAD;
    constexpr int UNITSP = UNITS + 2;
    constexpr int SEGS  = H / ROWS;
    constexpr int C8I   = IC / 8;
    constexpr int G16   = OC / 16;
    constexpr int NICB  = IC / 32;
    constexpr int C8O   = OC / 8;
    constexpr int TMAX  = NICB * 9;
    constexpr int NSTG  = UNITSP * C8I;
    static_assert(NICB % 2 == 0, "icb pair unroll");

    __shared__ ushort s_act[NSTG * 8];

    const int tid  = threadIdx.x;
    const int wv   = tid >> 6;
    const int lane = tid & 63;
    const int quad = lane >> 4;
    const int l16  = lane & 15;

    const int b   = blockIdx.x / SEGS;
    const int seg = blockIdx.x - b * SEGS;
    const int r0  = seg * ROWS;
    const int ocg = wv % OCGROUPS;
    const int pxg = wv / OCGROUPS;

    // ---- stage entire haloed strip, all IC, once (async direct-to-LDS) ----
    for (int c = tid; c < NSTG; c += 256) {
        int sub  = c / UNITSP;
        int unit = c - sub * UNITSP;
        int ry   = unit / WPAD, cx = unit - ry * WPAD;
        int gy   = r0 + ry - 1, gx = cx - 1;
        const ushort* src = zp;
        if (unit < UNITS && (unsigned)gy < (unsigned)H && (unsigned)gx < (unsigned)W)
            src = act_in + ((((long)b * C8I + sub) * H + gy) * W + gx) * 8;
        gload_lds16(src, &s_act[(size_t)(c - lane) * 8]);
    }
    __syncthreads();

    floatx4 acc[4][4];
#pragma unroll
    for (int i = 0; i < 4; ++i)
#pragma unroll
        for (int t = 0; t < 4; ++t) acc[i][t] = (floatx4)0.f;

    // per-lane read bases (include quad term)
    int bb[4];
#pragma unroll
    for (int t = 0; t < 4; ++t) {
        int pxl = pxg * 64 + t * 16 + l16;
        int py  = pxl / W, px = pxl - py * W;
        bb[t] = (py * WPAD + px) * 8 + quad * UNITSP * 8;
    }

    const short8* wb = (const short8*)wTs;
    const int  wbase = (ocg * 4) * 64 + lane;
    const long WSTEP = (long)G16 * 64;

    // depth-3 rotating weight prefetch
    short8 wpipe[3][4];
#pragma unroll
    for (int d = 0; d < 3; ++d)
#pragma unroll
        for (int i = 0; i < 4; ++i)
            wpipe[d][i] = wb[(long)d * WSTEP + wbase + i * 64];

    // A/B act pipeline: prologue reads step 0 (icb=0, ky=0, kx=0)
    short8 bfrA[4], bfrB[4];
#pragma unroll
    for (int t = 0; t < 4; ++t)
        bfrA[t] = *(const short8*)(&s_act[bb[t]]);

    constexpr int ICB_STRIDE = 4 * UNITSP * 8;   // ushort units per icb
    int tl = 0;
    int kbase = 0;
    for (int ic2 = 0; ic2 < NICB / 2; ++ic2) {
        const int kwrap = (ic2 + 1 < NICB / 2) ? kbase + 2 * ICB_STRIDE : 0;
#pragma unroll
        for (int s = 0; s < 18; ++s) {
            // next-step read offset (compile-time const part)
            const int ns   = (s + 1) % 18;
            const int nkk  = ns % 9;
            const int ncst = (ns / 9) * ICB_STRIDE + ((nkk / 3) * WPAD + (nkk % 3)) * 8;
            const int nbase = (s == 17) ? kwrap : kbase;
            const int slot = s % 3;              // tl%3 (18%3==0)
            if ((s & 1) == 0) {
                // current frags in A; read next into B
#pragma unroll
                for (int t = 0; t < 4; ++t)
                    bfrB[t] = *(const short8*)(&s_act[bb[t] + nbase + ncst]);
#pragma unroll
                for (int i = 0; i < 4; ++i)
#pragma unroll
                    for (int t = 0; t < 4; ++t)
                        acc[i][t] = __builtin_amdgcn_mfma_f32_16x16x32_bf16(
                            wpipe[slot][i], bfrA[t], acc[i][t], 0, 0, 0);
            } else {
#pragma unroll
                for (int t = 0; t < 4; ++t)
                    bfrA[t] = *(const short8*)(&s_act[bb[t] + nbase + ncst]);
#pragma unroll
                for (int i = 0; i < 4; ++i)
#pragma unroll
                    for (int t = 0; t < 4; ++t)
                        acc[i][t] = __builtin_amdgcn_mfma_f32_16x16x32_bf16(
                            wpipe[slot][i], bfrB[t], acc[i][t], 0, 0, 0);
            }
            // weight slot refill (step tl+3; wrap to dead-load 0)
            int tn = tl + 3;
            if (tn >= TMAX) tn = 0;
#pragma unroll
            for (int i = 0; i < 4; ++i)
                wpipe[slot][i] = wb[(long)tn * WSTEP + wbase + i * 64];
            ++tl;
        }
        kbase += 2 * ICB_STRIDE;
    }

    if constexpr (!POOL) {
#pragma unroll
        for (int i = 0; i < 4; ++i) {
            int oc0 = ocg * 64 + i * 16 + quad * 4;
            float4 bv = *(const float4*)(bias + oc0);
#pragma unroll
            for (int t = 0; t < 4; ++t) {
                int pxl = pxg * 64 + t * 16 + l16;
                int py  = pxl / W, px = pxl - py * W;
                long dst = ((((long)b * C8O + (oc0 >> 3)) * H + r0 + py) * W + px) * 8 + (oc0 & 7);
                float v0 = acc[i][t][0] + bv.x;
                float v1 = acc[i][t][1] + bv.y;
                float v2 = acc[i][t][2] + bv.z;
                float v3 = acc[i][t][3] + bv.w;
                ushort o[4];
                o[0] = f2bf(v0 > 0.f ? v0 : 0.f);
                o[1] = f2bf(v1 > 0.f ? v1 : 0.f);
                o[2] = f2bf(v2 > 0.f ? v2 : 0.f);
                o[3] = f2bf(v3 > 0.f ? v3 : 0.f);
                *(uint2*)(act_out + dst) = *(uint2*)o;
            }
        }
    } else {
        __syncthreads();                  // all waves done reading s_act
        ushort* s_pool = s_act;
        constexpr int PSTR = OC + 8;
        static_assert(ROWS * W * PSTR <= NSTG * 8, "pool scratch fits");
#pragma unroll
        for (int i = 0; i < 4; ++i) {
            int oc0 = ocg * 64 + i * 16 + quad * 4;
            float4 bv = *(const float4*)(bias + oc0);
#pragma unroll
            for (int t = 0; t < 4; ++t) {
                int pxl = pxg * 64 + t * 16 + l16;
                float v0 = acc[i][t][0] + bv.x;
                float v1 = acc[i][t][1] + bv.y;
                float v2 = acc[i][t][2] + bv.z;
                float v3 = acc[i][t][3] + bv.w;
                ushort o[4];
                o[0] = f2bf(v0 > 0.f ? v0 : 0.f);
                o[1] = f2bf(v1 > 0.f ? v1 : 0.f);
                o[2] = f2bf(v2 > 0.f ? v2 : 0.f);
                o[3] = f2bf(v3 > 0.f ? v3 : 0.f);
                *(uint2*)(&s_pool[pxl * PSTR + oc0]) = *(uint2*)o;
            }
        }
        __syncthreads();
        constexpr int PH = ROWS / 2, PW = W / 2, HOT = H / 2;
        const int pr0 = r0 / 2;
        ushort* s_feat = s_act + (NSTG * 8 - 4096);
        static_assert(!CLS || (ROWS * W * PSTR <= NSTG * 8 - 4096), "s_feat fits");
        static_assert(!CLS || (PH * PW == 16 && C8O * 8 == 256), "CLS geometry");
        for (int u = tid; u < PH * PW * C8O; u += 256) {
            int c8 = u % C8O;
            int pp = u / C8O;
            int xo = pp % PW, yo = pp / PW;
            const ushort* p00 = &s_pool[((2 * yo) * W + 2 * xo) * PSTR + c8 * 8];
            uint4 q0 = *(const uint4*)(p00);
            uint4 q1 = *(const uint4*)(p00 + PSTR);
            uint4 q2 = *(const uint4*)(p00 + W * PSTR);
            uint4 q3 = *(const uint4*)(p00 + W * PSTR + PSTR);
            const ushort* a0 = (const ushort*)&q0;
            const ushort* a1 = (const ushort*)&q1;
            const ushort* a2 = (const ushort*)&q2;
            const ushort* a3 = (const ushort*)&q3;
            ushort r[8];
#pragma unroll
            for (int j = 0; j < 8; ++j) {
                ushort m0 = a0[j] > a1[j] ? a0[j] : a1[j];
                ushort m1 = a2[j] > a3[j] ? a2[j] : a3[j];
                r[j] = m0 > m1 ? m0 : m1;
            }
            if constexpr (CLS) {
#pragma unroll
                for (int j = 0; j < 8; ++j)
                    s_feat[(c8 * 8 + j) * 16 + pp] = r[j];
            } else {
                long dst = ((((long)b * C8O + c8) * HOT + pr0 + yo) * PW + xo) * 8;
                *(uint4*)(act_out + dst) = *(uint4*)r;
            }
        }
        if constexpr (CLS) {
            __syncthreads();
            const int t = tids[b];
            const short* cbase = cwb + (long)t * 5 * 4096;
            for (int c = wv; c < 5; c += 4) {
                const short* wrow = cbase + (long)c * 4096;
                float s = 0.f;
#pragma unroll
                for (int j = 0; j < 8; ++j) {
                    short8 wv8 = *(const short8*)(wrow + lane * 8 + 512 * j);
                    short8 fv8 = *(const short8*)(s_feat + lane * 8 + 512 * j);
#pragma unroll
                    for (int e = 0; e < 8; ++e)
                        s += bf2f((ushort)wv8[e]) * bf2f((ushort)fv8[e]);
                }
#pragma unroll
                for (int off = 32; off > 0; off >>= 1) s += __shfl_down(s, off, 64);
                if (lane == 0) outp[(long)b * 5 + c] = s + cbv[t * 5 + c];
            }
        }
    }
}

// ---------------------------------------------------------------------------
extern "C" void kernel_launch(void* const* d_in, const int* in_sizes, int n_in,
                              void* d_out, int out_size, void* d_ws, size_t ws_size,
                              hipStream_t stream)
{
    const float* x   = (const float*)d_in[0];
    const int*   tid = (const int*)d_in[1];
    const float* w0 = (const float*)d_in[2];  const float* b0 = (const float*)d_in[3];
    const float* w1 = (const float*)d_in[4];  const float* b1 = (const float*)d_in[5];
    const float* w2 = (const float*)d_in[6];  const float* b2 = (const float*)d_in[7];
    const float* w3 = (const float*)d_in[8];  const float* b3 = (const float*)d_in[9];
    const float* w4 = (const float*)d_in[10]; const float* b4 = (const float*)d_in[11];
    const float* w5 = (const float*)d_in[12]; const float* b5 = (const float*)d_in[13];
    const float* cw = (const float*)d_in[14];
    const float* cb = (const float*)d_in[15];
    float* outp = (float*)d_out;

    const int B = in_sizes[0] / (3 * 32 * 32);   // 512

    // ---- ws layout (halfword units) ----
    short* wt0  = (short*)d_ws;
    short* wts1 = wt0 + N_W0;
    short* wts2 = wts1 + N_W1;
    short* wts3 = wts2 + N_W2;
    short* wts4 = wts3 + N_W3;
    short* wts5 = wts4 + N_W4;
    short* zp   = wts5 + N_W5;                    // 32 hw zero page
    short* cwb  = zp + 32;                        // bf16 classifier weights
    const size_t WT_HW = (size_t)N_WT_TOTAL + 32 + N_CWB;
    const size_t fixed_bytes = WT_HW * 2;

    int Bc = B;
    while (Bc > 2 && fixed_bytes + (size_t)Bc * 2 * 65536 * 2 > ws_size) Bc >>= 1;
    if (Bc < 2) Bc = 2;

    ushort* bufA = (ushort*)((short*)d_ws + WT_HW);
    ushort* bufB = bufA + (size_t)Bc * 65536;

    // ---- weight transforms + zero page + cw bf16, single fused launch ----
    wtransform_all<<<(N_ALL + 255) / 256, 256, 0, stream>>>(
        w0, w1, w2, w3, w4, w5, cw,
        wt0, wts1, wts2, wts3, wts4, wts5, zp, cwb);

    for (int cb0 = 0; cb0 < B; cb0 += Bc) {
        const float* xc = x + (size_t)cb0 * 3 * 32 * 32;
        const int* tidc = tid + cb0;
        float* outc = outp + (size_t)cb0 * 5;

        // conv0: 3->64 @32x32 -> bufA [Bc][8][32][32][8]
        conv0_mfma<<<Bc * 2, 256, 0, stream>>>(xc, wt0, b0, bufA);
        // conv1+pool: 64->64 @32x32 -> bufB [Bc][8][16][16][8]
        conv_so<64, 64, 32, 32, 8, 1, true, false><<<Bc * 4, 256, 0, stream>>>(
            bufA, wts1, b1, bufB, (ushort*)zp, nullptr, nullptr, nullptr, nullptr);
        // conv2: 64->128 @16x16 -> bufA [Bc][16][16][16][8]
        conv_so<64, 128, 16, 16, 8, 2, false, false><<<Bc * 2, 256, 0, stream>>>(
            bufB, wts2, b2, bufA, (ushort*)zp, nullptr, nullptr, nullptr, nullptr);
        // conv3+pool: 128->128 @16x16 -> bufB [Bc][16][8][8][8]
        conv_so<128, 128, 16, 16, 8, 2, true, false><<<Bc * 2, 256, 0, stream>>>(
            bufA, wts3, b3, bufB, (ushort*)zp, nullptr, nullptr, nullptr, nullptr);
        // conv4: 128->256 @8x8 -> bufA [Bc][32][8][8][8]
        conv_so<128, 256, 8, 8, 8, 4, false, false><<<Bc, 256, 0, stream>>>(
            bufB, wts4, b4, bufA, (ushort*)zp, nullptr, nullptr, nullptr, nullptr);
        // conv5+pool+classifier: 256->256 @8x8 -> outc
        conv_so<256, 256, 8, 8, 8, 4, true, true><<<Bc, 256, 0, stream>>>(
            bufA, wts5, b5, bufB, (ushort*)zp, tidc, cwb, cb, outc);
    }
}

// Round 9
// 261.576 us; speedup vs baseline: 1.2318x; 1.2318x over previous
//
#include <hip/hip_runtime.h>

// ---------------------------------------------------------------------------
// Round 21: CONSOLIDATION. Four structural K-loop variants (R15/R17/R19/R20)
// all regressed vs the compiler-scheduled simple loop -> restore R14/R16's
// K-loop exactly (VGPR 84, ~45us per 38.7GFLOP layer). Keep the two verified
// wins: CLS fusion in conv5 (R18) now with bf16 cwb dot (cheaper than fp32),
// and the single fused weight-transform launch.
// NC8HW8 bf16 activations, linear frag-order weights, fp32 in / fp32 out.
// ---------------------------------------------------------------------------

typedef __attribute__((ext_vector_type(8))) short short8;
typedef __attribute__((ext_vector_type(4))) float floatx4;
typedef unsigned int uint;
typedef unsigned short ushort;

__device__ __forceinline__ ushort f2bf(float f) {
    uint u = __float_as_uint(f);
    return (ushort)((u + 0x7fffu + ((u >> 16) & 1u)) >> 16);
}
__device__ __forceinline__ float bf2f(ushort h) {
    return __uint_as_float(((uint)h) << 16);
}

// async global->LDS, 16 bytes per lane, dest = wave-uniform base + lane*16
typedef const __attribute__((address_space(1))) unsigned int* gas_ptr;
typedef __attribute__((address_space(3))) unsigned int* las_ptr;
__device__ __forceinline__ void gload_lds16(const void* g, void* l) {
    __builtin_amdgcn_global_load_lds((gas_ptr)g, (las_ptr)l, 16, 0, 0);
}

// ---------------- fused weight transform (single launch) -------------------
__device__ __forceinline__ void wlin_one(
    const float* __restrict__ src, short* __restrict__ dst, int OC, int IC, int o)
{
    int j    = o & 7;
    int lane = (o >> 3) & 63;
    int r    = o >> 9;
    int G16  = OC >> 4;
    int g    = r % G16;  r /= G16;
    int kk   = r % 9;
    int icb  = r / 9;
    int oc = g * 16 + (lane & 15);
    int ic = icb * 32 + (lane >> 4) * 8 + j;
    dst[o] = (short)f2bf(src[((long)oc * IC + ic) * 9 + kk]);
}

#define N_W0 2048
#define N_W1 36864
#define N_W2 73728
#define N_W3 147456
#define N_W4 294912
#define N_W5 589824
#define N_CWB (100 * 4096)
#define N_WT_TOTAL (N_W0 + N_W1 + N_W2 + N_W3 + N_W4 + N_W5)
#define N_ALL (N_WT_TOTAL + N_CWB)

__global__ __launch_bounds__(256) void wtransform_all(
    const float* __restrict__ w0, const float* __restrict__ w1,
    const float* __restrict__ w2, const float* __restrict__ w3,
    const float* __restrict__ w4, const float* __restrict__ w5,
    const float* __restrict__ cw,
    short* __restrict__ wt0, short* __restrict__ wts1, short* __restrict__ wts2,
    short* __restrict__ wts3, short* __restrict__ wts4, short* __restrict__ wts5,
    short* __restrict__ zp, short* __restrict__ cwb)
{
    if (blockIdx.x == 0 && threadIdx.x < 32) zp[threadIdx.x] = 0;  // zero page
    int idx = blockIdx.x * 256 + threadIdx.x;
    if (idx < N_W0) {
        int oc = idx >> 5, k = idx & 31;
        wt0[idx] = (k < 27) ? (short)f2bf(w0[oc * 27 + k]) : (short)0;
        return;
    }
    idx -= N_W0;
    if (idx < N_W1) { wlin_one(w1, wts1, 64, 64, idx); return; }
    idx -= N_W1;
    if (idx < N_W2) { wlin_one(w2, wts2, 128, 64, idx); return; }
    idx -= N_W2;
    if (idx < N_W3) { wlin_one(w3, wts3, 128, 128, idx); return; }
    idx -= N_W3;
    if (idx < N_W4) { wlin_one(w4, wts4, 256, 128, idx); return; }
    idx -= N_W4;
    if (idx < N_W5) { wlin_one(w5, wts5, 256, 256, idx); return; }
    idx -= N_W5;
    if (idx < N_CWB) cwb[idx] = (short)f2bf(cw[idx]);
}

// ---------------- conv0 MFMA: 3->64 @32x32, NCHW fp32 in, NC8HW8 bf16 out
__global__ __launch_bounds__(256, 2) void conv0_mfma(
    const float* __restrict__ x, const short* __restrict__ wT0,
    const float* __restrict__ b0, ushort* __restrict__ out)
{
    __shared__ float  s_x[3 * 18 * 34];
    __shared__ ushort s_b[4 * 512 * 8];

    const int tid  = threadIdx.x;
    const int wv   = tid >> 6;
    const int lane = tid & 63;
    const int quad = lane >> 4;
    const int l16  = lane & 15;
    const int b    = blockIdx.x >> 1;
    const int r0   = (blockIdx.x & 1) * 16;

    for (int idx = tid; idx < 3 * 18 * 34; idx += 256) {
        int c   = idx / 612;
        int rem = idx - c * 612;
        int ry  = rem / 34, rx = rem - ry * 34;
        int gy  = r0 + ry - 1, gx = rx - 1;
        float v = 0.f;
        if (gy >= 0 && gy < 32 && gx >= 0 && gx < 32)
            v = x[(((long)b * 3 + c) * 32 + gy) * 32 + gx];
        s_x[idx] = v;
    }
    __syncthreads();

#pragma unroll
    for (int rep = 0; rep < 2; ++rep) {
        int pxl = rep * 256 + tid;
        int py = pxl >> 5, px = pxl & 31;
        ushort v[32];
#pragma unroll
        for (int c = 0; c < 3; ++c)
#pragma unroll
            for (int ky = 0; ky < 3; ++ky)
#pragma unroll
                for (int kx = 0; kx < 3; ++kx)
                    v[c * 9 + ky * 3 + kx] = f2bf(s_x[c * 612 + (py + ky) * 34 + (px + kx)]);
#pragma unroll
        for (int k = 27; k < 32; ++k) v[k] = 0;
#pragma unroll
        for (int q = 0; q < 4; ++q)
            *(uint4*)(&s_b[(q * 512 + pxl) * 8]) = *(const uint4*)(v + q * 8);
    }
    __syncthreads();

    floatx4 acc[4][8];
#pragma unroll
    for (int i = 0; i < 4; ++i)
#pragma unroll
        for (int t = 0; t < 8; ++t) acc[i][t] = (floatx4)0.f;

    short8 afr[4];
#pragma unroll
    for (int i = 0; i < 4; ++i)
        afr[i] = *(const short8*)(wT0 + (i * 16 + l16) * 32 + quad * 8);
#pragma unroll
    for (int t = 0; t < 8; ++t) {
        int pxl = wv * 128 + t * 16 + l16;
        short8 bfr = *(const short8*)(&s_b[(quad * 512 + pxl) * 8]);
#pragma unroll
        for (int i = 0; i < 4; ++i)
            acc[i][t] = __builtin_amdgcn_mfma_f32_16x16x32_bf16(afr[i], bfr, acc[i][t], 0, 0, 0);
    }

#pragma unroll
    for (int i = 0; i < 4; ++i) {
        int oc0 = i * 16 + quad * 4;
        float4 bv = *(const float4*)(b0 + oc0);
#pragma unroll
        for (int t = 0; t < 8; ++t) {
            int pxl = wv * 128 + t * 16 + l16;
            int py = pxl >> 5, px = pxl & 31;
            long dst = ((((long)b * 8 + (oc0 >> 3)) * 32 + r0 + py) * 32 + px) * 8 + (oc0 & 7);
            float v0 = acc[i][t][0] + bv.x;
            float v1 = acc[i][t][1] + bv.y;
            float v2 = acc[i][t][2] + bv.z;
            float v3 = acc[i][t][3] + bv.w;
            ushort o[4];
            o[0] = f2bf(v0 > 0.f ? v0 : 0.f);
            o[1] = f2bf(v1 > 0.f ? v1 : 0.f);
            o[2] = f2bf(v2 > 0.f ? v2 : 0.f);
            o[3] = f2bf(v3 > 0.f ? v3 : 0.f);
            *(uint2*)(out + dst) = *(uint2*)o;
        }
    }
}

// ---------------- stage-once conv3x3+ReLU (+pool, +optional classifier) ----
// Block = 4 waves, one strip of ROWS rows. Wave = 64 oc x 64 px (4x4 frags).
// K-loop: the R14/R16 compiler-scheduled simple loop + depth-3 weight pipe.
// DO NOT software-pipeline the ds_reads here: R15/R17/R19/R20 all regressed.
template<int IC, int OC, int H, int W, int ROWS, int OCGROUPS, bool POOL, bool CLS>
__global__ __launch_bounds__(256, 3) void conv_so(
    const ushort* __restrict__ act_in,  // [B][IC/8][H][W][8]
    const short*  __restrict__ wTs,     // linear frag-order bf16
    const float*  __restrict__ bias,
    ushort* __restrict__ act_out,       // [B][OC/8][H'][W'][8] (pooled if POOL)
    const ushort* __restrict__ zp,      // 64B zero page
    const int*   __restrict__ tids,     // CLS only
    const short* __restrict__ cwb,      // CLS only (bf16)
    const float* __restrict__ cbv,      // CLS only
    float*       __restrict__ outp)     // CLS only
{
    constexpr int WPAD  = W + 2;
    constexpr int RPAD  = ROWS + 2;
    constexpr int UNITS = RPAD * WPAD;
    constexpr int UNITSP = UNITS + 2;
    constexpr int SEGS  = H / ROWS;
    constexpr int C8I   = IC / 8;
    constexpr int G16   = OC / 16;
    constexpr int NICB  = IC / 32;
    constexpr int C8O   = OC / 8;
    constexpr int TMAX  = NICB * 9;
    constexpr int NSTG  = UNITSP * C8I;

    __shared__ ushort s_act[NSTG * 8];

    const int tid  = threadIdx.x;
    const int wv   = tid >> 6;
    const int lane = tid & 63;
    const int quad = lane >> 4;
    const int l16  = lane & 15;

    const int b   = blockIdx.x / SEGS;
    const int seg = blockIdx.x - b * SEGS;
    const int r0  = seg * ROWS;
    const int ocg = wv % OCGROUPS;
    const int pxg = wv / OCGROUPS;

    // ---- stage entire haloed strip, all IC, once (async direct-to-LDS) ----
    for (int c = tid; c < NSTG; c += 256) {
        int sub  = c / UNITSP;
        int unit = c - sub * UNITSP;
        int ry   = unit / WPAD, cx = unit - ry * WPAD;
        int gy   = r0 + ry - 1, gx = cx - 1;
        const ushort* src = zp;
        if (unit < UNITS && (unsigned)gy < (unsigned)H && (unsigned)gx < (unsigned)W)
            src = act_in + ((((long)b * C8I + sub) * H + gy) * W + gx) * 8;
        gload_lds16(src, &s_act[(size_t)(c - lane) * 8]);
    }
    __syncthreads();   // compiler drains vmcnt(0) here

    floatx4 acc[4][4];
#pragma unroll
    for (int i = 0; i < 4; ++i)
#pragma unroll
        for (int t = 0; t < 4; ++t) acc[i][t] = (floatx4)0.f;

    int bbase[4];
#pragma unroll
    for (int t = 0; t < 4; ++t) {
        int pxl = pxg * 64 + t * 16 + l16;
        int py  = pxl / W, px = pxl - py * W;
        bbase[t] = (py * WPAD + px) * 8;
    }

    const short8* wb = (const short8*)wTs;
    const int  wbase = (ocg * 4) * 64 + lane;     // short8 index within a step
    const long WSTEP = (long)G16 * 64;            // short8 stride per step

    // ---- depth-3 rotating weight prefetch ----
    short8 wpipe[3][4];
#pragma unroll
    for (int d = 0; d < 3; ++d)
#pragma unroll
        for (int i = 0; i < 4; ++i)
            wpipe[d][i] = wb[(long)d * WSTEP + wbase + i * 64];

    int tl = 0;
    for (int icb = 0; icb < NICB; ++icb) {
#pragma unroll
        for (int kk = 0; kk < 9; ++kk) {
            const int ky = kk / 3, kx = kk - ky * 3;
            const int koff = ((icb * 4 + quad) * UNITSP + ky * WPAD + kx) * 8;
            short8 bfr[4];
#pragma unroll
            for (int t = 0; t < 4; ++t)
                bfr[t] = *(const short8*)(&s_act[bbase[t] + koff]);
            const int slot = kk % 3;   // compile-time after unroll
#pragma unroll
            for (int i = 0; i < 4; ++i)
#pragma unroll
                for (int t = 0; t < 4; ++t)
                    acc[i][t] = __builtin_amdgcn_mfma_f32_16x16x32_bf16(
                        wpipe[slot][i], bfr[t], acc[i][t], 0, 0, 0);
            int tn = tl + 3;
            if (tn >= TMAX) tn = 0;
#pragma unroll
            for (int i = 0; i < 4; ++i)
                wpipe[slot][i] = wb[(long)tn * WSTEP + wbase + i * 64];
            ++tl;
        }
    }

    if constexpr (!POOL) {
#pragma unroll
        for (int i = 0; i < 4; ++i) {
            int oc0 = ocg * 64 + i * 16 + quad * 4;
            float4 bv = *(const float4*)(bias + oc0);
#pragma unroll
            for (int t = 0; t < 4; ++t) {
                int pxl = pxg * 64 + t * 16 + l16;
                int py  = pxl / W, px = pxl - py * W;
                long dst = ((((long)b * C8O + (oc0 >> 3)) * H + r0 + py) * W + px) * 8 + (oc0 & 7);
                float v0 = acc[i][t][0] + bv.x;
                float v1 = acc[i][t][1] + bv.y;
                float v2 = acc[i][t][2] + bv.z;
                float v3 = acc[i][t][3] + bv.w;
                ushort o[4];
                o[0] = f2bf(v0 > 0.f ? v0 : 0.f);
                o[1] = f2bf(v1 > 0.f ? v1 : 0.f);
                o[2] = f2bf(v2 > 0.f ? v2 : 0.f);
                o[3] = f2bf(v3 > 0.f ? v3 : 0.f);
                *(uint2*)(act_out + dst) = *(uint2*)o;
            }
        }
    } else {
        __syncthreads();                  // all waves done reading s_act
        ushort* s_pool = s_act;
        constexpr int PSTR = OC + 8;      // multiple of 8 -> 16B-aligned chunks
        static_assert(ROWS * W * PSTR <= NSTG * 8, "pool scratch fits");
#pragma unroll
        for (int i = 0; i < 4; ++i) {
            int oc0 = ocg * 64 + i * 16 + quad * 4;
            float4 bv = *(const float4*)(bias + oc0);
#pragma unroll
            for (int t = 0; t < 4; ++t) {
                int pxl = pxg * 64 + t * 16 + l16;
                float v0 = acc[i][t][0] + bv.x;
                float v1 = acc[i][t][1] + bv.y;
                float v2 = acc[i][t][2] + bv.z;
                float v3 = acc[i][t][3] + bv.w;
                ushort o[4];
                o[0] = f2bf(v0 > 0.f ? v0 : 0.f);
                o[1] = f2bf(v1 > 0.f ? v1 : 0.f);
                o[2] = f2bf(v2 > 0.f ? v2 : 0.f);
                o[3] = f2bf(v3 > 0.f ? v3 : 0.f);
                *(uint2*)(&s_pool[pxl * PSTR + oc0]) = *(uint2*)o;
            }
        }
        __syncthreads();
        constexpr int PH = ROWS / 2, PW = W / 2, HOT = H / 2;
        const int pr0 = r0 / 2;
        ushort* s_feat = s_act + (NSTG * 8 - 4096);
        static_assert(!CLS || (ROWS * W * PSTR <= NSTG * 8 - 4096), "s_feat fits");
        static_assert(!CLS || (PH * PW == 16 && C8O * 8 == 256), "CLS geometry");
        for (int u = tid; u < PH * PW * C8O; u += 256) {
            int c8 = u % C8O;
            int pp = u / C8O;
            int xo = pp % PW, yo = pp / PW;
            const ushort* p00 = &s_pool[((2 * yo) * W + 2 * xo) * PSTR + c8 * 8];
            uint4 q0 = *(const uint4*)(p00);
            uint4 q1 = *(const uint4*)(p00 + PSTR);
            uint4 q2 = *(const uint4*)(p00 + W * PSTR);
            uint4 q3 = *(const uint4*)(p00 + W * PSTR + PSTR);
            const ushort* a0 = (const ushort*)&q0;
            const ushort* a1 = (const ushort*)&q1;
            const ushort* a2 = (const ushort*)&q2;
            const ushort* a3 = (const ushort*)&q3;
            ushort r[8];
#pragma unroll
            for (int j = 0; j < 8; ++j) {
                ushort m0 = a0[j] > a1[j] ? a0[j] : a1[j];
                ushort m1 = a2[j] > a3[j] ? a2[j] : a3[j];
                r[j] = m0 > m1 ? m0 : m1;
            }
            if constexpr (CLS) {
                // d = (c8*8+j)*16 + pp  (reference flatten order)
#pragma unroll
                for (int j = 0; j < 8; ++j)
                    s_feat[(c8 * 8 + j) * 16 + pp] = r[j];
            } else {
                long dst = ((((long)b * C8O + c8) * HOT + pr0 + yo) * PW + xo) * 8;
                *(uint4*)(act_out + dst) = *(uint4*)r;
            }
        }
        if constexpr (CLS) {
            __syncthreads();
            const int t = tids[b];
            const short* cbase = cwb + (long)t * 5 * 4096;
            for (int c = wv; c < 5; c += 4) {
                const short* wrow = cbase + (long)c * 4096;
                float s = 0.f;
#pragma unroll
                for (int j = 0; j < 8; ++j) {
                    short8 wv8 = *(const short8*)(wrow + lane * 8 + 512 * j);
                    short8 fv8 = *(const short8*)(s_feat + lane * 8 + 512 * j);
#pragma unroll
                    for (int e = 0; e < 8; ++e)
                        s += bf2f((ushort)wv8[e]) * bf2f((ushort)fv8[e]);
                }
#pragma unroll
                for (int off = 32; off > 0; off >>= 1) s += __shfl_down(s, off, 64);
                if (lane == 0) outp[(long)b * 5 + c] = s + cbv[t * 5 + c];
            }
        }
    }
}

// ---------------------------------------------------------------------------
extern "C" void kernel_launch(void* const* d_in, const int* in_sizes, int n_in,
                              void* d_out, int out_size, void* d_ws, size_t ws_size,
                              hipStream_t stream)
{
    const float* x   = (const float*)d_in[0];
    const int*   tid = (const int*)d_in[1];
    const float* w0 = (const float*)d_in[2];  const float* b0 = (const float*)d_in[3];
    const float* w1 = (const float*)d_in[4];  const float* b1 = (const float*)d_in[5];
    const float* w2 = (const float*)d_in[6];  const float* b2 = (const float*)d_in[7];
    const float* w3 = (const float*)d_in[8];  const float* b3 = (const float*)d_in[9];
    const float* w4 = (const float*)d_in[10]; const float* b4 = (const float*)d_in[11];
    const float* w5 = (const float*)d_in[12]; const float* b5 = (const float*)d_in[13];
    const float* cw = (const float*)d_in[14];
    const float* cb = (const float*)d_in[15];
    float* outp = (float*)d_out;

    const int B = in_sizes[0] / (3 * 32 * 32);   // 512

    // ---- ws layout (halfword units) ----
    short* wt0  = (short*)d_ws;
    short* wts1 = wt0 + N_W0;
    short* wts2 = wts1 + N_W1;
    short* wts3 = wts2 + N_W2;
    short* wts4 = wts3 + N_W3;
    short* wts5 = wts4 + N_W4;
    short* zp   = wts5 + N_W5;                    // 32 hw zero page
    short* cwb  = zp + 32;                        // bf16 classifier weights
    const size_t WT_HW = (size_t)N_WT_TOTAL + 32 + N_CWB;
    const size_t fixed_bytes = WT_HW * 2;

    int Bc = B;
    while (Bc > 2 && fixed_bytes + (size_t)Bc * 2 * 65536 * 2 > ws_size) Bc >>= 1;
    if (Bc < 2) Bc = 2;

    ushort* bufA = (ushort*)((short*)d_ws + WT_HW);
    ushort* bufB = bufA + (size_t)Bc * 65536;

    // ---- weight transforms + zero page + cw bf16, single fused launch ----
    wtransform_all<<<(N_ALL + 255) / 256, 256, 0, stream>>>(
        w0, w1, w2, w3, w4, w5, cw,
        wt0, wts1, wts2, wts3, wts4, wts5, zp, cwb);

    for (int cb0 = 0; cb0 < B; cb0 += Bc) {
        const float* xc = x + (size_t)cb0 * 3 * 32 * 32;
        const int* tidc = tid + cb0;
        float* outc = outp + (size_t)cb0 * 5;

        // conv0: 3->64 @32x32 -> bufA [Bc][8][32][32][8]
        conv0_mfma<<<Bc * 2, 256, 0, stream>>>(xc, wt0, b0, bufA);
        // conv1+pool: 64->64 @32x32 -> bufB [Bc][8][16][16][8]
        conv_so<64, 64, 32, 32, 8, 1, true, false><<<Bc * 4, 256, 0, stream>>>(
            bufA, wts1, b1, bufB, (ushort*)zp, nullptr, nullptr, nullptr, nullptr);
        // conv2: 64->128 @16x16 -> bufA [Bc][16][16][16][8]
        conv_so<64, 128, 16, 16, 8, 2, false, false><<<Bc * 2, 256, 0, stream>>>(
            bufB, wts2, b2, bufA, (ushort*)zp, nullptr, nullptr, nullptr, nullptr);
        // conv3+pool: 128->128 @16x16 -> bufB [Bc][16][8][8][8]
        conv_so<128, 128, 16, 16, 8, 2, true, false><<<Bc * 2, 256, 0, stream>>>(
            bufA, wts3, b3, bufB, (ushort*)zp, nullptr, nullptr, nullptr, nullptr);
        // conv4: 128->256 @8x8 -> bufA [Bc][32][8][8][8]
        conv_so<128, 256, 8, 8, 8, 4, false, false><<<Bc, 256, 0, stream>>>(
            bufB, wts4, b4, bufA, (ushort*)zp, nullptr, nullptr, nullptr, nullptr);
        // conv5+pool+classifier: 256->256 @8x8 -> outc
        conv_so<256, 256, 8, 8, 8, 4, true, true><<<Bc, 256, 0, stream>>>(
            bufA, wts5, b5, bufB, (ushort*)zp, tidc, cwb, cb, outc);
    }
}